// Round 10
// baseline (234.381 us; speedup 1.0000x reference)
//
#include <hip/hip_runtime.h>
#include <hip/hip_bf16.h>
#include <math.h>

// N=50000 nodes, E=600000 edges, H=128.
#define HD 128
#define APAD 136   // LDS row stride in ushorts (+8 pad: 272 B rows, 16B-aligned, 2-way bank alias = free)

typedef short bf16x8 __attribute__((ext_vector_type(8)));
typedef float f32x4 __attribute__((ext_vector_type(4)));

static __device__ __forceinline__ unsigned short f2bf(float f) {
  __hip_bfloat16 b = __float2bfloat16(f);
  return *(unsigned short*)&b;
}
static __device__ __forceinline__ float bflo(unsigned int u) {
  return __uint_as_float(u << 16);
}
static __device__ __forceinline__ float bfhi(unsigned int u) {
  return __uint_as_float(u & 0xffff0000u);
}

// ---------------------------------------------------------------------------
// K0: pack weights into MFMA B-fragment order (blocks 0-39) + edge histogram
// (blocks 40+).  hist atomicAdd return value = edge's within-node slot ->
// eoff[e]; removes ALL atomics from the scatter phase (round-9 proven).
// ---------------------------------------------------------------------------
__global__ __launch_bounds__(256) void k_frag_hist(
    const float* __restrict__ enc_w, const float* __restrict__ M_w,
    const float* __restrict__ U_w,
    unsigned short* __restrict__ encf, unsigned short* __restrict__ Pf,
    unsigned short* __restrict__ Qf, unsigned short* __restrict__ Uf,
    const int* __restrict__ ei, int* __restrict__ cnt,
    int* __restrict__ eoff, int E) {
  const int b = blockIdx.x;
  if (b >= 40) {
    const int e = (b - 40) * 256 + threadIdx.x;
    if (e < E) eoff[e] = atomicAdd(&cnt[ei[E + e]], 1);
    return;
  }
  const float* W; unsigned short* F; int KS; int lb;
  if (b < 8)       { W = enc_w + HD;     F = encf; KS = 4; lb = b; }
  else if (b < 16) { W = M_w;            F = Pf;   KS = 4; lb = b - 8; }
  else if (b < 24) { W = M_w + HD * HD;  F = Qf;   KS = 4; lb = b - 16; }
  else             { W = U_w;            F = Uf;   KS = 8; lb = b - 24; }
  const int gid = lb * 256 + threadIdx.x;
  const int lane = gid & 63;
  const int ks = (gid >> 6) % KS;
  const int tile = gid / (64 * KS);
  const int col = tile * 16 + (lane & 15);
  const int k0 = ks * 32 + (lane >> 4) * 8;
  unsigned short v[8];
#pragma unroll
  for (int j = 0; j < 8; ++j) v[j] = f2bf(W[(size_t)(k0 + j) * HD + col]);
  unsigned short* dst = F + ((size_t)(tile * KS + ks) * 64 + lane) * 8;
#pragma unroll
  for (int j = 0; j < 8; ++j) dst[j] = v[j];
}

// ---------------------------------------------------------------------------
// K_scan1: single-dispatch scan via decoupled lookback (round-8/9 proven).
// row_ptr = exclusive prefix, cursor = inclusive prefix (= row_end).
// ---------------------------------------------------------------------------
__global__ __launch_bounds__(256) void k_scan1(
    int* __restrict__ cursor, int* __restrict__ row_ptr,
    unsigned long long* __restrict__ flags, int N) {
  __shared__ int s[256];
  __shared__ int poff_sh;
  const int t = threadIdx.x, b = blockIdx.x;
  const int base = b * 1024 + t * 4;
  int v[4], sum = 0;
#pragma unroll
  for (int i = 0; i < 4; ++i) {
    v[i] = (base + i < N) ? cursor[base + i] : 0;
    sum += v[i];
  }
  s[t] = sum;
  __syncthreads();
  for (int off = 1; off < 256; off <<= 1) {
    int xv = (t >= off) ? s[t - off] : 0;
    __syncthreads();
    if (t >= off) s[t] += xv;
    __syncthreads();
  }
  if (t == 0)
    atomicExch(&flags[b], ((unsigned long long)(unsigned)s[255] << 32) | 1ull);
  if (t < 64) {
    int acc = 0;
    if (t < b) {
      unsigned long long f;
      do { f = atomicAdd(&flags[t], 0ull); } while (!(f & 1ull));
      acc = (int)(f >> 32);
    }
#pragma unroll
    for (int o = 32; o > 0; o >>= 1) acc += __shfl_down(acc, o);
    if (t == 0) poff_sh = acc;
  }
  __syncthreads();
  int run = s[t] - sum + poff_sh;
#pragma unroll
  for (int i = 0; i < 4; ++i) {
    if (base + i < N) {
      row_ptr[base + i] = run;          // exclusive (row start)
      cursor[base + i]  = run + v[i];   // inclusive (row end)
      run += v[i];
    }
  }
}

// ---------------------------------------------------------------------------
// K1: merged atomic-free scatter (blocks 0..eb-1) + MFMA encoder/P/Q
// (blocks eb..).  (round-9 proven)
// ---------------------------------------------------------------------------
__global__ __launch_bounds__(256, 4) void k_scatter_enc(
    const int* __restrict__ ei, const float* __restrict__ edge_attr,
    const int* __restrict__ row_ptr, const int* __restrict__ eoff,
    int2* __restrict__ epack, int E, int eb,
    const float* __restrict__ x, const float* __restrict__ pre_h,
    const float* __restrict__ enc_w, const float* __restrict__ enc_b,
    const float* __restrict__ M_b,
    const unsigned short* __restrict__ encf, const unsigned short* __restrict__ Pf,
    const unsigned short* __restrict__ Qf,
    unsigned short* __restrict__ zg, unsigned short* __restrict__ Pg,
    unsigned short* __restrict__ Qg) {
  __shared__ unsigned short phs[16 * APAD];  // pre_h bf16; later P staging
  __shared__ unsigned short zsh[16 * APAD];  // z bf16; later Q staging
  __shared__ float xs[16];
  const int t = threadIdx.x;

  if (blockIdx.x < (unsigned)eb) {
    const int e = blockIdx.x * 256 + t;
    if (e < E) {
      const int tgt = ei[E + e];
      const int pos = row_ptr[tgt] + eoff[e];
      epack[pos] = make_int2(ei[e], __float_as_int(edge_attr[e]));
    }
    return;
  }

  const int n0 = (blockIdx.x - eb) * 16;
  {
    const int r = t >> 4, c0 = (t & 15) * 8;
    const float4 a = *(const float4*)&pre_h[(size_t)(n0 + r) * HD + c0];
    const float4 b = *(const float4*)&pre_h[(size_t)(n0 + r) * HD + c0 + 4];
    unsigned short* d = &phs[r * APAD + c0];
    d[0] = f2bf(a.x); d[1] = f2bf(a.y); d[2] = f2bf(a.z); d[3] = f2bf(a.w);
    d[4] = f2bf(b.x); d[5] = f2bf(b.y); d[6] = f2bf(b.z); d[7] = f2bf(b.w);
  }
  if (t < 16) xs[t] = x[n0 + t];
  __syncthreads();

  const int w = t >> 6, l = t & 63;
  const int m = l & 15, q = l >> 4;

  bf16x8 af[4];
#pragma unroll
  for (int ks = 0; ks < 4; ++ks)
    af[ks] = *(const bf16x8*)&phs[m * APAD + ks * 32 + q * 8];
  f32x4 acc[2] = {{0, 0, 0, 0}, {0, 0, 0, 0}};
#pragma unroll
  for (int tt = 0; tt < 2; ++tt) {
    const int tn = 2 * w + tt;
#pragma unroll
    for (int ks = 0; ks < 4; ++ks) {
      const bf16x8 bf = *(const bf16x8*)&encf[((size_t)(tn * 4 + ks) * 64 + l) * 8];
      acc[tt] = __builtin_amdgcn_mfma_f32_16x16x32_bf16(af[ks], bf, acc[tt], 0, 0, 0);
    }
  }
#pragma unroll
  for (int tt = 0; tt < 2; ++tt) {
    const int col = (2 * w + tt) * 16 + m;
    const float bb = enc_b[col];
    const float w0 = enc_w[col];  // row 0 (x feature)
#pragma unroll
    for (int r = 0; r < 4; ++r) {
      const int row = q * 4 + r;
      const float zv = fmaxf(acc[tt][r] + bb + xs[row] * w0, 0.0f);
      zsh[row * APAD + col] = f2bf(zv);
    }
  }
  __syncthreads();

  bf16x8 az[4];
#pragma unroll
  for (int ks = 0; ks < 4; ++ks)
    az[ks] = *(const bf16x8*)&zsh[m * APAD + ks * 32 + q * 8];
  {
    const int r = t >> 4, c0 = (t & 15) * 8;
    *(uint4*)&zg[(size_t)(n0 + r) * HD + c0] = *(const uint4*)&zsh[r * APAD + c0];
  }
  __syncthreads();

  f32x4 pacc[2] = {{0, 0, 0, 0}, {0, 0, 0, 0}};
  f32x4 qacc[2] = {{0, 0, 0, 0}, {0, 0, 0, 0}};
#pragma unroll
  for (int tt = 0; tt < 2; ++tt) {
    const int tn = 2 * w + tt;
#pragma unroll
    for (int ks = 0; ks < 4; ++ks) {
      const bf16x8 bp = *(const bf16x8*)&Pf[((size_t)(tn * 4 + ks) * 64 + l) * 8];
      const bf16x8 bq = *(const bf16x8*)&Qf[((size_t)(tn * 4 + ks) * 64 + l) * 8];
      pacc[tt] = __builtin_amdgcn_mfma_f32_16x16x32_bf16(az[ks], bp, pacc[tt], 0, 0, 0);
      qacc[tt] = __builtin_amdgcn_mfma_f32_16x16x32_bf16(az[ks], bq, qacc[tt], 0, 0, 0);
    }
  }
#pragma unroll
  for (int tt = 0; tt < 2; ++tt) {
    const int col = (2 * w + tt) * 16 + m;
    const float mb = M_b[col];
#pragma unroll
    for (int r = 0; r < 4; ++r) {
      const int row = q * 4 + r;
      phs[row * APAD + col] = f2bf(pacc[tt][r] + mb);  // P staging (bias folded)
      zsh[row * APAD + col] = f2bf(qacc[tt][r]);       // Q staging
    }
  }
  __syncthreads();
  {
    const int r = t >> 4, c0 = (t & 15) * 8;
    *(uint4*)&Pg[(size_t)(n0 + r) * HD + c0] = *(const uint4*)&phs[r * APAD + c0];
    *(uint4*)&Qg[(size_t)(n0 + r) * HD + c0] = *(const uint4*)&zsh[r * APAD + c0];
  }
}

// ---------------------------------------------------------------------------
// K2: fused gather-max + U-GEMM + decoder.  16 nodes/block (N%16==0 -> no
// tail), 4 waves, ONE node per 16-lane group (serial gather chain HALVED vs
// the 32-node version; 3125 blocks = 12.2/CU for tail smoothing).
// LDS ~10.4KB; unroll-8 gather (128B in flight/lane, tail clamped).
// ---------------------------------------------------------------------------
__global__ __launch_bounds__(256, 8) void k_gu(
    const unsigned short* __restrict__ zg, const unsigned short* __restrict__ Pg,
    const unsigned short* __restrict__ Qg, const float* __restrict__ w_attr,
    const int* __restrict__ row_ptr, const int* __restrict__ row_end,
    const int2* __restrict__ epack, const unsigned short* __restrict__ Uf,
    const float* __restrict__ U_b, const float* __restrict__ dec_w,
    const float* __restrict__ dec_b,
    float* __restrict__ h_out, float* __restrict__ y_out,
    float* __restrict__ hpart, int N) {
  __shared__ unsigned short zsh[16 * APAD];
  __shared__ unsigned short ash[16 * APAD];
  __shared__ float hcol[HD];
  __shared__ float dacc[16];
  __shared__ float pr[16][16];
  const int t = threadIdx.x;
  const int n0 = blockIdx.x * 16;

  {
    const int r = t >> 4, c0 = (t & 15) * 8;
    const int n = min(n0 + r, N - 1);
    *(uint4*)&zsh[r * APAD + c0] = *(const uint4*)&zg[(size_t)n * HD + c0];
  }
  if (t < 16) dacc[t] = 0.0f;
  if (t < HD) hcol[t] = 0.0f;

  const int w = t >> 6, l = t & 63;
  const int g = l >> 4, j = l & 15;

  float wv[8];
  {
    const float4 wa = *(const float4*)&w_attr[j * 8];
    const float4 wb = *(const float4*)&w_attr[j * 8 + 4];
    wv[0] = wa.x; wv[1] = wa.y; wv[2] = wa.z; wv[3] = wa.w;
    wv[4] = wb.x; wv[5] = wb.y; wv[6] = wb.z; wv[7] = wb.w;
  }
  // ---- gather-max: lane-group g -> node w*4+g (ONE node, halved chain) ----
  {
    const int r = w * 4 + g;
    const int n = n0 + r;
    const int nc = min(n, N - 1);
    const int rs = row_ptr[nc], re = row_end[nc];
    float acc[8];
#pragma unroll
    for (int c = 0; c < 8; ++c) acc[c] = -INFINITY;
    for (int e = rs; e < re; e += 8) {
      int2 pk[8];
#pragma unroll
      for (int u = 0; u < 8; ++u) pk[u] = epack[min(e + u, re - 1)];
      uint4 qv[8];
#pragma unroll
      for (int u = 0; u < 8; ++u)
        qv[u] = *(const uint4*)&Qg[(size_t)pk[u].x * HD + j * 8];
#pragma unroll
      for (int u = 0; u < 8; ++u) {
        const float a = __int_as_float(pk[u].y);
        const unsigned int qq[4] = {qv[u].x, qv[u].y, qv[u].z, qv[u].w};
#pragma unroll
        for (int c = 0; c < 4; ++c) {
          acc[2 * c]     = fmaxf(acc[2 * c],     fmaf(a, wv[2 * c],     bflo(qq[c])));
          acc[2 * c + 1] = fmaxf(acc[2 * c + 1], fmaf(a, wv[2 * c + 1], bfhi(qq[c])));
        }
      }
    }
    float res[8];
    if (n < N && re > rs) {
      const uint4 pv = *(const uint4*)&Pg[(size_t)n * HD + j * 8];
      const unsigned int pp[4] = {pv.x, pv.y, pv.z, pv.w};
#pragma unroll
      for (int c = 0; c < 4; ++c) {
        res[2 * c]     = fmaxf(bflo(pp[c]) + acc[2 * c],     0.0f);
        res[2 * c + 1] = fmaxf(bfhi(pp[c]) + acc[2 * c + 1], 0.0f);
      }
    } else {
#pragma unroll
      for (int c = 0; c < 8; ++c) res[c] = 0.0f;
    }
    uint4 st;
    st.x = (unsigned)f2bf(res[0]) | ((unsigned)f2bf(res[1]) << 16);
    st.y = (unsigned)f2bf(res[2]) | ((unsigned)f2bf(res[3]) << 16);
    st.z = (unsigned)f2bf(res[4]) | ((unsigned)f2bf(res[5]) << 16);
    st.w = (unsigned)f2bf(res[6]) | ((unsigned)f2bf(res[7]) << 16);
    *(uint4*)&ash[r * APAD + j * 8] = st;
  }
  __syncthreads();

  // ---- U-GEMM: wave w -> cols [32w, 32w+32), all 16 rows ----
  const int m = l & 15, q = l >> 4;
  bf16x8 afz[4], afa[4];
#pragma unroll
  for (int ks = 0; ks < 4; ++ks) {
    afz[ks] = *(const bf16x8*)&zsh[m * APAD + ks * 32 + q * 8];
    afa[ks] = *(const bf16x8*)&ash[m * APAD + ks * 32 + q * 8];
  }
  f32x4 acc4[2] = {{0, 0, 0, 0}, {0, 0, 0, 0}};
#pragma unroll
  for (int tt = 0; tt < 2; ++tt) {
    const int tn = w * 2 + tt;
#pragma unroll
    for (int ks = 0; ks < 8; ++ks) {
      const bf16x8 bf = *(const bf16x8*)&Uf[((size_t)(tn * 8 + ks) * 64 + l) * 8];
      const bf16x8 a = (ks < 4) ? afz[ks] : afa[ks - 4];
      acc4[tt] = __builtin_amdgcn_mfma_f32_16x16x32_bf16(a, bf, acc4[tt], 0, 0, 0);
    }
  }
  float dp[4] = {0.0f, 0.0f, 0.0f, 0.0f};
#pragma unroll
  for (int tt = 0; tt < 2; ++tt) {
    const int col = (w * 2 + tt) * 16 + m;
    const float ub = U_b[col];
    const float dw = dec_w[HD + col];
    float s4 = 0.0f;
#pragma unroll
    for (int r = 0; r < 4; ++r) {
      const int rowl = q * 4 + r;
      const int n = n0 + rowl;
      float hv = fmaxf(acc4[tt][r] + ub, 0.0f);
      if (n < N) h_out[(size_t)n * HD + col] = hv; else hv = 0.0f;
      s4 += hv;
      dp[r] += hv * dw;
    }
    atomicAdd(&hcol[col], s4);
  }
  // reduce decoder h-part across the 16 lanes sharing the same 4 rows
#pragma unroll
  for (int off = 1; off < 16; off <<= 1) {
#pragma unroll
    for (int r = 0; r < 4; ++r) dp[r] += __shfl_xor(dp[r], off);
  }
  if ((l & 15) == 0) {
#pragma unroll
    for (int r = 0; r < 4; ++r) atomicAdd(&dacc[q * 4 + r], dp[r]);
  }

  // ---- decoder z-part: thread t -> node t>>4, cols (t&15)*8 .. +7 ----
  {
    const int r2 = t >> 4, s = t & 15;
    float part = 0.0f;
#pragma unroll
    for (int c = 0; c < 4; ++c) {
      const int kk = s * 8 + 2 * c;
      const unsigned int zu = *(const unsigned int*)&zsh[r2 * APAD + kk];
      part += bflo(zu) * dec_w[kk] + bfhi(zu) * dec_w[kk + 1];
    }
    pr[r2][s] = part;
  }
  __syncthreads();

  if (t < HD) hpart[(size_t)blockIdx.x * HD + t] = hcol[t];
  if (t < 16 && n0 + t < N) {
    float d = dec_b[0] + dacc[t];
#pragma unroll
    for (int s = 0; s < 16; ++s) d += pr[t][s];
    y_out[n0 + t] = 1.0f / (1.0f + expf(-d));
  }
}

// ---------------------------------------------------------------------------
// K3: parallel hpart reduction + terminator in ONE dispatch (round-8/9 proven).
// ---------------------------------------------------------------------------
__global__ __launch_bounds__(256) void k_hred_ter(
    const float* __restrict__ hpart, float* __restrict__ hsum,
    int* __restrict__ done,
    const float* __restrict__ ter_w, const float* __restrict__ ter_b,
    float* __restrict__ out, float invN, int NB, int nblk) {
  __shared__ float sh[HD];
  __shared__ float r2[2];
  __shared__ int last;
  const int t = threadIdx.x;
  const int col = t & (HD - 1);
  const int half = t >> 7;
  float acc = 0.0f;
  for (int r = blockIdx.x * 2 + half; r < NB; r += nblk * 2)
    acc += hpart[(size_t)r * HD + col];
  if (half) sh[col] = acc;
  __syncthreads();
  if (!half) atomicAdd(&hsum[col], acc + sh[col]);
  __threadfence();
  __syncthreads();
  if (t == 0) last = (atomicAdd(done, 1) == nblk - 1);
  __syncthreads();
  if (!last) return;
  float v = 0.0f;
  if (t < HD) {
    const float cs = atomicAdd(&hsum[t], 0.0f);  // atomic load (bypass L1)
    v = (cs * invN) * (ter_w[t] + ter_w[HD + t]);
  }
#pragma unroll
  for (int o = 32; o > 0; o >>= 1) v += __shfl_down(v, o);
  if (t < HD && (t & 63) == 0) r2[t >> 6] = v;
  __syncthreads();
  if (t == 0) out[0] = r2[0] + r2[1] + ter_b[0];
}

// ---------------------------------------------------------------------------
extern "C" void kernel_launch(void* const* d_in, const int* in_sizes, int n_in,
                              void* d_out, int out_size, void* d_ws, size_t ws_size,
                              hipStream_t stream) {
  const float* x        = (const float*)d_in[0];
  const float* pre_h    = (const float*)d_in[1];
  const float* edge_attr= (const float*)d_in[2];
  const float* enc_w    = (const float*)d_in[3];
  const float* enc_b    = (const float*)d_in[4];
  const float* M_w      = (const float*)d_in[5];
  const float* M_b      = (const float*)d_in[6];
  const float* U_w      = (const float*)d_in[7];
  const float* U_b      = (const float*)d_in[8];
  const float* dec_w    = (const float*)d_in[9];
  const float* dec_b    = (const float*)d_in[10];
  const float* ter_w    = (const float*)d_in[11];
  const float* ter_b    = (const float*)d_in[12];
  const int*   edge_idx = (const int*)d_in[13];

  const int N = in_sizes[0];      // 50000
  const int E = in_sizes[2];      // 600000
  const size_t NH = (size_t)N * HD;

  float* out = (float*)d_out;
  float* h_out = out;             // [0, N*H)
  float* y_out = out + NH;        // [N*H, N*H+N)
  float* ter_out = out + NH + N;

  // ws layout (bf16): zg | Pg | Qg | cursor(N) | flags(64 ull) | done(2 int)
  //                   | hsum(128 f) | row_ptr(N) | epack(E int2) | eoff(E int)
  //                   | encf | Pf | Qf | Uf | hpart
  unsigned short* zg = (unsigned short*)d_ws;
  unsigned short* Pg = zg + NH;
  unsigned short* Qg = Pg + NH;
  int*   cursor   = (int*)(Qg + NH);
  unsigned long long* flags = (unsigned long long*)(cursor + N);  // N*4 %8==0
  int*   done     = (int*)(flags + 64);
  float* hsum     = (float*)(done + 2);
  int*   row_ptr  = (int*)(hsum + HD);
  int2*  epack    = (int2*)(row_ptr + N);
  int*   eoff     = (int*)(epack + E);
  unsigned short* encf = (unsigned short*)(eoff + E);
  unsigned short* Pf   = encf + 8 * 4 * 64 * 8;
  unsigned short* Qf   = Pf + 8 * 4 * 64 * 8;
  unsigned short* Uf   = Qf + 8 * 4 * 64 * 8;
  float* hpart = (float*)(Uf + 16 * 256 * 8);

  const size_t zero_bytes = (size_t)N * 4 + 64 * 8 + 2 * 4 + HD * 4;
  hipMemsetAsync(cursor, 0, zero_bytes, stream);

  const int scan_blocks = (N + 1023) / 1024;  // 49
  const int eb = (E + 255) / 256;             // 2344
  const int nb16 = (N + 15) / 16;             // 3125

  k_frag_hist<<<40 + eb, 256, 0, stream>>>(enc_w, M_w, U_w, encf, Pf, Qf, Uf,
                                           edge_idx, cursor, eoff, E);
  k_scan1<<<scan_blocks, 256, 0, stream>>>(cursor, row_ptr, flags, N);
  k_scatter_enc<<<eb + N / 16, 256, 0, stream>>>(
      edge_idx, edge_attr, row_ptr, eoff, epack, E, eb,
      x, pre_h, enc_w, enc_b, M_b, encf, Pf, Qf, zg, Pg, Qg);
  k_gu<<<nb16, 256, 0, stream>>>(
      zg, Pg, Qg, M_w + 256 * HD, row_ptr, cursor, epack, Uf,
      U_b, dec_w, dec_b, h_out, y_out, hpart, N);
  k_hred_ter<<<64, 256, 0, stream>>>(hpart, hsum, done, ter_w, ter_b, ter_out,
                                     1.0f / (float)N, nb16, 64);
}

// Round 11
// 220.526 us; speedup vs baseline: 1.0628x; 1.0628x over previous
//
#include <hip/hip_runtime.h>
#include <hip/hip_bf16.h>
#include <math.h>

// N=50000 nodes, E=600000 edges, H=128.
#define HD 128
#define APAD 136   // LDS row stride in ushorts (+8 pad: 272 B rows, 16B-aligned, 2-way bank alias = free)

typedef short bf16x8 __attribute__((ext_vector_type(8)));
typedef float f32x4 __attribute__((ext_vector_type(4)));
typedef unsigned int u32x4 __attribute__((ext_vector_type(4)));

static __device__ __forceinline__ unsigned short f2bf(float f) {
  __hip_bfloat16 b = __float2bfloat16(f);
  return *(unsigned short*)&b;
}
static __device__ __forceinline__ float bflo(unsigned int u) {
  return __uint_as_float(u << 16);
}
static __device__ __forceinline__ float bfhi(unsigned int u) {
  return __uint_as_float(u & 0xffff0000u);
}

// ---------------------------------------------------------------------------
// K0: pack weights into MFMA B-fragment order (blocks 0-39) + edge histogram
// (blocks 40+).  hist atomicAdd return value = edge's within-node slot ->
// eoff[e]; removes ALL atomics from the scatter phase (round-9 proven).
// ---------------------------------------------------------------------------
__global__ __launch_bounds__(256) void k_frag_hist(
    const float* __restrict__ enc_w, const float* __restrict__ M_w,
    const float* __restrict__ U_w,
    unsigned short* __restrict__ encf, unsigned short* __restrict__ Pf,
    unsigned short* __restrict__ Qf, unsigned short* __restrict__ Uf,
    const int* __restrict__ ei, int* __restrict__ cnt,
    int* __restrict__ eoff, int E) {
  const int b = blockIdx.x;
  if (b >= 40) {
    const int e = (b - 40) * 256 + threadIdx.x;
    if (e < E) eoff[e] = atomicAdd(&cnt[ei[E + e]], 1);
    return;
  }
  const float* W; unsigned short* F; int KS; int lb;
  if (b < 8)       { W = enc_w + HD;     F = encf; KS = 4; lb = b; }
  else if (b < 16) { W = M_w;            F = Pf;   KS = 4; lb = b - 8; }
  else if (b < 24) { W = M_w + HD * HD;  F = Qf;   KS = 4; lb = b - 16; }
  else             { W = U_w;            F = Uf;   KS = 8; lb = b - 24; }
  const int gid = lb * 256 + threadIdx.x;
  const int lane = gid & 63;
  const int ks = (gid >> 6) % KS;
  const int tile = gid / (64 * KS);
  const int col = tile * 16 + (lane & 15);
  const int k0 = ks * 32 + (lane >> 4) * 8;
  unsigned short v[8];
#pragma unroll
  for (int j = 0; j < 8; ++j) v[j] = f2bf(W[(size_t)(k0 + j) * HD + col]);
  unsigned short* dst = F + ((size_t)(tile * KS + ks) * 64 + lane) * 8;
#pragma unroll
  for (int j = 0; j < 8; ++j) dst[j] = v[j];
}

// ---------------------------------------------------------------------------
// K_scan1: single-dispatch scan via decoupled lookback (round-8/9 proven).
// row_ptr = exclusive prefix, cursor = inclusive prefix (= row_end).
// ---------------------------------------------------------------------------
__global__ __launch_bounds__(256) void k_scan1(
    int* __restrict__ cursor, int* __restrict__ row_ptr,
    unsigned long long* __restrict__ flags, int N) {
  __shared__ int s[256];
  __shared__ int poff_sh;
  const int t = threadIdx.x, b = blockIdx.x;
  const int base = b * 1024 + t * 4;
  int v[4], sum = 0;
#pragma unroll
  for (int i = 0; i < 4; ++i) {
    v[i] = (base + i < N) ? cursor[base + i] : 0;
    sum += v[i];
  }
  s[t] = sum;
  __syncthreads();
  for (int off = 1; off < 256; off <<= 1) {
    int xv = (t >= off) ? s[t - off] : 0;
    __syncthreads();
    if (t >= off) s[t] += xv;
    __syncthreads();
  }
  if (t == 0)
    atomicExch(&flags[b], ((unsigned long long)(unsigned)s[255] << 32) | 1ull);
  if (t < 64) {
    int acc = 0;
    if (t < b) {
      unsigned long long f;
      do { f = atomicAdd(&flags[t], 0ull); } while (!(f & 1ull));
      acc = (int)(f >> 32);
    }
#pragma unroll
    for (int o = 32; o > 0; o >>= 1) acc += __shfl_down(acc, o);
    if (t == 0) poff_sh = acc;
  }
  __syncthreads();
  int run = s[t] - sum + poff_sh;
#pragma unroll
  for (int i = 0; i < 4; ++i) {
    if (base + i < N) {
      row_ptr[base + i] = run;          // exclusive (row start)
      cursor[base + i]  = run + v[i];   // inclusive (row end)
      run += v[i];
    }
  }
}

// ---------------------------------------------------------------------------
// K1: merged atomic-free scatter (blocks 0..eb-1) + MFMA encoder/P/Q
// (blocks eb..).  (round-9 proven)
// ---------------------------------------------------------------------------
__global__ __launch_bounds__(256, 4) void k_scatter_enc(
    const int* __restrict__ ei, const float* __restrict__ edge_attr,
    const int* __restrict__ row_ptr, const int* __restrict__ eoff,
    int2* __restrict__ epack, int E, int eb,
    const float* __restrict__ x, const float* __restrict__ pre_h,
    const float* __restrict__ enc_w, const float* __restrict__ enc_b,
    const float* __restrict__ M_b,
    const unsigned short* __restrict__ encf, const unsigned short* __restrict__ Pf,
    const unsigned short* __restrict__ Qf,
    unsigned short* __restrict__ zg, unsigned short* __restrict__ Pg,
    unsigned short* __restrict__ Qg) {
  __shared__ unsigned short phs[16 * APAD];  // pre_h bf16; later P staging
  __shared__ unsigned short zsh[16 * APAD];  // z bf16; later Q staging
  __shared__ float xs[16];
  const int t = threadIdx.x;

  if (blockIdx.x < (unsigned)eb) {
    const int e = blockIdx.x * 256 + t;
    if (e < E) {
      const int tgt = ei[E + e];
      const int pos = row_ptr[tgt] + eoff[e];
      epack[pos] = make_int2(ei[e], __float_as_int(edge_attr[e]));
    }
    return;
  }

  const int n0 = (blockIdx.x - eb) * 16;
  {
    const int r = t >> 4, c0 = (t & 15) * 8;
    const float4 a = *(const float4*)&pre_h[(size_t)(n0 + r) * HD + c0];
    const float4 b = *(const float4*)&pre_h[(size_t)(n0 + r) * HD + c0 + 4];
    unsigned short* d = &phs[r * APAD + c0];
    d[0] = f2bf(a.x); d[1] = f2bf(a.y); d[2] = f2bf(a.z); d[3] = f2bf(a.w);
    d[4] = f2bf(b.x); d[5] = f2bf(b.y); d[6] = f2bf(b.z); d[7] = f2bf(b.w);
  }
  if (t < 16) xs[t] = x[n0 + t];
  __syncthreads();

  const int w = t >> 6, l = t & 63;
  const int m = l & 15, q = l >> 4;

  bf16x8 af[4];
#pragma unroll
  for (int ks = 0; ks < 4; ++ks)
    af[ks] = *(const bf16x8*)&phs[m * APAD + ks * 32 + q * 8];
  f32x4 acc[2] = {{0, 0, 0, 0}, {0, 0, 0, 0}};
#pragma unroll
  for (int tt = 0; tt < 2; ++tt) {
    const int tn = 2 * w + tt;
#pragma unroll
    for (int ks = 0; ks < 4; ++ks) {
      const bf16x8 bf = *(const bf16x8*)&encf[((size_t)(tn * 4 + ks) * 64 + l) * 8];
      acc[tt] = __builtin_amdgcn_mfma_f32_16x16x32_bf16(af[ks], bf, acc[tt], 0, 0, 0);
    }
  }
#pragma unroll
  for (int tt = 0; tt < 2; ++tt) {
    const int col = (2 * w + tt) * 16 + m;
    const float bb = enc_b[col];
    const float w0 = enc_w[col];  // row 0 (x feature)
#pragma unroll
    for (int r = 0; r < 4; ++r) {
      const int row = q * 4 + r;
      const float zv = fmaxf(acc[tt][r] + bb + xs[row] * w0, 0.0f);
      zsh[row * APAD + col] = f2bf(zv);
    }
  }
  __syncthreads();

  bf16x8 az[4];
#pragma unroll
  for (int ks = 0; ks < 4; ++ks)
    az[ks] = *(const bf16x8*)&zsh[m * APAD + ks * 32 + q * 8];
  {
    const int r = t >> 4, c0 = (t & 15) * 8;
    *(uint4*)&zg[(size_t)(n0 + r) * HD + c0] = *(const uint4*)&zsh[r * APAD + c0];
  }
  __syncthreads();

  f32x4 pacc[2] = {{0, 0, 0, 0}, {0, 0, 0, 0}};
  f32x4 qacc[2] = {{0, 0, 0, 0}, {0, 0, 0, 0}};
#pragma unroll
  for (int tt = 0; tt < 2; ++tt) {
    const int tn = 2 * w + tt;
#pragma unroll
    for (int ks = 0; ks < 4; ++ks) {
      const bf16x8 bp = *(const bf16x8*)&Pf[((size_t)(tn * 4 + ks) * 64 + l) * 8];
      const bf16x8 bq = *(const bf16x8*)&Qf[((size_t)(tn * 4 + ks) * 64 + l) * 8];
      pacc[tt] = __builtin_amdgcn_mfma_f32_16x16x32_bf16(az[ks], bp, pacc[tt], 0, 0, 0);
      qacc[tt] = __builtin_amdgcn_mfma_f32_16x16x32_bf16(az[ks], bq, qacc[tt], 0, 0, 0);
    }
  }
#pragma unroll
  for (int tt = 0; tt < 2; ++tt) {
    const int col = (2 * w + tt) * 16 + m;
    const float mb = M_b[col];
#pragma unroll
    for (int r = 0; r < 4; ++r) {
      const int row = q * 4 + r;
      phs[row * APAD + col] = f2bf(pacc[tt][r] + mb);  // P staging (bias folded)
      zsh[row * APAD + col] = f2bf(qacc[tt][r]);       // Q staging
    }
  }
  __syncthreads();
  {
    const int r = t >> 4, c0 = (t & 15) * 8;
    *(uint4*)&Pg[(size_t)(n0 + r) * HD + c0] = *(const uint4*)&phs[r * APAD + c0];
    *(uint4*)&Qg[(size_t)(n0 + r) * HD + c0] = *(const uint4*)&zsh[r * APAD + c0];
  }
}

// ---------------------------------------------------------------------------
// K2: fused gather-max + U-GEMM + decoder.  32 nodes/block, 4 waves
// (round-9 proven shape, 51.4us; round-10's 16-node variant doubled HBM
// traffic and regressed -- reverted).
// NEW: non-temporal hints on all ZERO-REUSE traffic (zg/Pg staging loads,
// h_out/y_out stores) so the 4MB/XCD L2 keeps Qg rows (the only stream
// with reuse: 154MB demand vs 75MB L2-fill).
// ---------------------------------------------------------------------------
__global__ __launch_bounds__(256, 6) void k_gu(
    const unsigned short* __restrict__ zg, const unsigned short* __restrict__ Pg,
    const unsigned short* __restrict__ Qg, const float* __restrict__ w_attr,
    const int* __restrict__ row_ptr, const int* __restrict__ row_end,
    const int2* __restrict__ epack, const unsigned short* __restrict__ Uf,
    const float* __restrict__ U_b, const float* __restrict__ dec_w,
    const float* __restrict__ dec_b,
    float* __restrict__ h_out, float* __restrict__ y_out,
    float* __restrict__ hpart, int N) {
  __shared__ unsigned short zsh[32 * APAD];
  __shared__ unsigned short ash[32 * APAD];
  __shared__ float hcol[HD];
  __shared__ float dacc[32];
  __shared__ float pr[32][8];
  const int t = threadIdx.x;
  const int n0 = blockIdx.x * 32;

  {
    const int r = t >> 3, c0 = (t & 7) * 16;
    const int n = min(n0 + r, N - 1);
    const u32x4 z0 = __builtin_nontemporal_load(
        (const u32x4*)&zg[(size_t)n * HD + c0]);
    const u32x4 z1 = __builtin_nontemporal_load(
        (const u32x4*)&zg[(size_t)n * HD + c0 + 8]);
    *(u32x4*)&zsh[r * APAD + c0]     = z0;
    *(u32x4*)&zsh[r * APAD + c0 + 8] = z1;
  }
  if (t < 32) dacc[t] = 0.0f;
  if (t < HD) hcol[t] = 0.0f;

  const int w = t >> 6, l = t & 63;
  const int g = l >> 4, j = l & 15;

  float wv[8];
  {
    const float4 wa = *(const float4*)&w_attr[j * 8];
    const float4 wb = *(const float4*)&w_attr[j * 8 + 4];
    wv[0] = wa.x; wv[1] = wa.y; wv[2] = wa.z; wv[3] = wa.w;
    wv[4] = wb.x; wv[5] = wb.y; wv[6] = wb.z; wv[7] = wb.w;
  }
#pragma unroll
  for (int i = 0; i < 2; ++i) {
    const int r = w * 8 + g * 2 + i;
    const int n = n0 + r;
    const int nc = min(n, N - 1);
    const int rs = row_ptr[nc], re = row_end[nc];
    float acc[8];
#pragma unroll
    for (int c = 0; c < 8; ++c) acc[c] = -INFINITY;
    for (int e = rs; e < re; e += 8) {
      int2 pk[8];
#pragma unroll
      for (int u = 0; u < 8; ++u) pk[u] = epack[min(e + u, re - 1)];
      uint4 qv[8];
#pragma unroll
      for (int u = 0; u < 8; ++u)
        qv[u] = *(const uint4*)&Qg[(size_t)pk[u].x * HD + j * 8];
#pragma unroll
      for (int u = 0; u < 8; ++u) {
        const float a = __int_as_float(pk[u].y);
        const unsigned int qq[4] = {qv[u].x, qv[u].y, qv[u].z, qv[u].w};
#pragma unroll
        for (int c = 0; c < 4; ++c) {
          acc[2 * c]     = fmaxf(acc[2 * c],     fmaf(a, wv[2 * c],     bflo(qq[c])));
          acc[2 * c + 1] = fmaxf(acc[2 * c + 1], fmaf(a, wv[2 * c + 1], bfhi(qq[c])));
        }
      }
    }
    float res[8];
    if (n < N && re > rs) {
      const u32x4 pv = __builtin_nontemporal_load(
          (const u32x4*)&Pg[(size_t)n * HD + j * 8]);
#pragma unroll
      for (int c = 0; c < 4; ++c) {
        res[2 * c]     = fmaxf(bflo(pv[c]) + acc[2 * c],     0.0f);
        res[2 * c + 1] = fmaxf(bfhi(pv[c]) + acc[2 * c + 1], 0.0f);
      }
    } else {
#pragma unroll
      for (int c = 0; c < 8; ++c) res[c] = 0.0f;
    }
    uint4 st;
    st.x = (unsigned)f2bf(res[0]) | ((unsigned)f2bf(res[1]) << 16);
    st.y = (unsigned)f2bf(res[2]) | ((unsigned)f2bf(res[3]) << 16);
    st.z = (unsigned)f2bf(res[4]) | ((unsigned)f2bf(res[5]) << 16);
    st.w = (unsigned)f2bf(res[6]) | ((unsigned)f2bf(res[7]) << 16);
    *(uint4*)&ash[r * APAD + j * 8] = st;
  }
  __syncthreads();

  const int mt = w & 1, nh = w >> 1;
  const int m = mt * 16 + (l & 15), q = l >> 4;
  bf16x8 afz[4], afa[4];
#pragma unroll
  for (int ks = 0; ks < 4; ++ks) {
    afz[ks] = *(const bf16x8*)&zsh[m * APAD + ks * 32 + q * 8];
    afa[ks] = *(const bf16x8*)&ash[m * APAD + ks * 32 + q * 8];
  }
  f32x4 acc4[4] = {{0, 0, 0, 0}, {0, 0, 0, 0}, {0, 0, 0, 0}, {0, 0, 0, 0}};
#pragma unroll
  for (int tt = 0; tt < 4; ++tt) {
    const int tn = nh * 4 + tt;
#pragma unroll
    for (int ks = 0; ks < 8; ++ks) {
      const bf16x8 bf = *(const bf16x8*)&Uf[((size_t)(tn * 8 + ks) * 64 + l) * 8];
      const bf16x8 a = (ks < 4) ? afz[ks] : afa[ks - 4];
      acc4[tt] = __builtin_amdgcn_mfma_f32_16x16x32_bf16(a, bf, acc4[tt], 0, 0, 0);
    }
  }
  float dp[4] = {0.0f, 0.0f, 0.0f, 0.0f};
#pragma unroll
  for (int tt = 0; tt < 4; ++tt) {
    const int col = (nh * 4 + tt) * 16 + (l & 15);
    const float ub = U_b[col];
    const float dw = dec_w[HD + col];
    float s4 = 0.0f;
#pragma unroll
    for (int r = 0; r < 4; ++r) {
      const int rowl = mt * 16 + q * 4 + r;
      const int n = n0 + rowl;
      float hv = fmaxf(acc4[tt][r] + ub, 0.0f);
      if (n < N) __builtin_nontemporal_store(hv, &h_out[(size_t)n * HD + col]);
      else hv = 0.0f;
      s4 += hv;
      dp[r] += hv * dw;
    }
    atomicAdd(&hcol[col], s4);
  }
#pragma unroll
  for (int off = 1; off < 16; off <<= 1) {
#pragma unroll
    for (int r = 0; r < 4; ++r) dp[r] += __shfl_xor(dp[r], off);
  }
  if ((l & 15) == 0) {
#pragma unroll
    for (int r = 0; r < 4; ++r) atomicAdd(&dacc[mt * 16 + q * 4 + r], dp[r]);
  }
  {
    const int r2 = t >> 3, s = t & 7;
    float part = 0.0f;
#pragma unroll
    for (int c = 0; c < 8; ++c) {
      const int kk = s * 16 + 2 * c;
      const unsigned int zu = *(const unsigned int*)&zsh[r2 * APAD + kk];
      part += bflo(zu) * dec_w[kk] + bfhi(zu) * dec_w[kk + 1];
    }
    pr[r2][s] = part;
  }
  __syncthreads();

  if (t < HD) hpart[(size_t)blockIdx.x * HD + t] = hcol[t];
  if (t < 32 && n0 + t < N) {
    float d = dec_b[0] + dacc[t];
#pragma unroll
    for (int s = 0; s < 8; ++s) d += pr[t][s];
    __builtin_nontemporal_store(1.0f / (1.0f + expf(-d)), &y_out[n0 + t]);
  }
}

// ---------------------------------------------------------------------------
// K3: parallel hpart reduction + terminator in ONE dispatch (round-8/9 proven).
// ---------------------------------------------------------------------------
__global__ __launch_bounds__(256) void k_hred_ter(
    const float* __restrict__ hpart, float* __restrict__ hsum,
    int* __restrict__ done,
    const float* __restrict__ ter_w, const float* __restrict__ ter_b,
    float* __restrict__ out, float invN, int NB, int nblk) {
  __shared__ float sh[HD];
  __shared__ float r2[2];
  __shared__ int last;
  const int t = threadIdx.x;
  const int col = t & (HD - 1);
  const int half = t >> 7;
  float acc = 0.0f;
  for (int r = blockIdx.x * 2 + half; r < NB; r += nblk * 2)
    acc += hpart[(size_t)r * HD + col];
  if (half) sh[col] = acc;
  __syncthreads();
  if (!half) atomicAdd(&hsum[col], acc + sh[col]);
  __threadfence();
  __syncthreads();
  if (t == 0) last = (atomicAdd(done, 1) == nblk - 1);
  __syncthreads();
  if (!last) return;
  float v = 0.0f;
  if (t < HD) {
    const float cs = atomicAdd(&hsum[t], 0.0f);  // atomic load (bypass L1)
    v = (cs * invN) * (ter_w[t] + ter_w[HD + t]);
  }
#pragma unroll
  for (int o = 32; o > 0; o >>= 1) v += __shfl_down(v, o);
  if (t < HD && (t & 63) == 0) r2[t >> 6] = v;
  __syncthreads();
  if (t == 0) out[0] = r2[0] + r2[1] + ter_b[0];
}

// ---------------------------------------------------------------------------
extern "C" void kernel_launch(void* const* d_in, const int* in_sizes, int n_in,
                              void* d_out, int out_size, void* d_ws, size_t ws_size,
                              hipStream_t stream) {
  const float* x        = (const float*)d_in[0];
  const float* pre_h    = (const float*)d_in[1];
  const float* edge_attr= (const float*)d_in[2];
  const float* enc_w    = (const float*)d_in[3];
  const float* enc_b    = (const float*)d_in[4];
  const float* M_w      = (const float*)d_in[5];
  const float* M_b      = (const float*)d_in[6];
  const float* U_w      = (const float*)d_in[7];
  const float* U_b      = (const float*)d_in[8];
  const float* dec_w    = (const float*)d_in[9];
  const float* dec_b    = (const float*)d_in[10];
  const float* ter_w    = (const float*)d_in[11];
  const float* ter_b    = (const float*)d_in[12];
  const int*   edge_idx = (const int*)d_in[13];

  const int N = in_sizes[0];      // 50000
  const int E = in_sizes[2];      // 600000
  const size_t NH = (size_t)N * HD;

  float* out = (float*)d_out;
  float* h_out = out;             // [0, N*H)
  float* y_out = out + NH;        // [N*H, N*H+N)
  float* ter_out = out + NH + N;

  // ws layout (bf16): zg | Pg | Qg | cursor(N) | flags(64 ull) | done(2 int)
  //                   | hsum(128 f) | row_ptr(N) | epack(E int2) | eoff(E int)
  //                   | encf | Pf | Qf | Uf | hpart
  unsigned short* zg = (unsigned short*)d_ws;
  unsigned short* Pg = zg + NH;
  unsigned short* Qg = Pg + NH;
  int*   cursor   = (int*)(Qg + NH);
  unsigned long long* flags = (unsigned long long*)(cursor + N);  // N*4 %8==0
  int*   done     = (int*)(flags + 64);
  float* hsum     = (float*)(done + 2);
  int*   row_ptr  = (int*)(hsum + HD);
  int2*  epack    = (int2*)(row_ptr + N);
  int*   eoff     = (int*)(epack + E);
  unsigned short* encf = (unsigned short*)(eoff + E);
  unsigned short* Pf   = encf + 8 * 4 * 64 * 8;
  unsigned short* Qf   = Pf + 8 * 4 * 64 * 8;
  unsigned short* Uf   = Qf + 8 * 4 * 64 * 8;
  float* hpart = (float*)(Uf + 16 * 256 * 8);

  const size_t zero_bytes = (size_t)N * 4 + 64 * 8 + 2 * 4 + HD * 4;
  hipMemsetAsync(cursor, 0, zero_bytes, stream);

  const int scan_blocks = (N + 1023) / 1024;  // 49
  const int eb = (E + 255) / 256;             // 2344
  const int nb32 = (N + 31) / 32;             // 1563

  k_frag_hist<<<40 + eb, 256, 0, stream>>>(enc_w, M_w, U_w, encf, Pf, Qf, Uf,
                                           edge_idx, cursor, eoff, E);
  k_scan1<<<scan_blocks, 256, 0, stream>>>(cursor, row_ptr, flags, N);
  k_scatter_enc<<<eb + N / 16, 256, 0, stream>>>(
      edge_idx, edge_attr, row_ptr, eoff, epack, E, eb,
      x, pre_h, enc_w, enc_b, M_b, encf, Pf, Qf, zg, Pg, Qg);
  k_gu<<<nb32, 256, 0, stream>>>(
      zg, Pg, Qg, M_w + 256 * HD, row_ptr, cursor, epack, Uf,
      U_b, dec_w, dec_b, h_out, y_out, hpart, N);
  k_hred_ter<<<64, 256, 0, stream>>>(hpart, hsum, done, ter_w, ter_b, ter_out,
                                     1.0f / (float)N, nb32, 64);
}

// Round 12
// 220.370 us; speedup vs baseline: 1.0636x; 1.0007x over previous
//
#include <hip/hip_runtime.h>
#include <hip/hip_bf16.h>
#include <math.h>

// N=50000 nodes, E=600000 edges, H=128.
#define HD 128
#define APAD 136   // LDS row stride in ushorts (+8 pad: 272 B rows, 16B-aligned, 2-way bank alias = free)

typedef short bf16x8 __attribute__((ext_vector_type(8)));
typedef float f32x4 __attribute__((ext_vector_type(4)));

static __device__ __forceinline__ unsigned short f2bf(float f) {
  __hip_bfloat16 b = __float2bfloat16(f);
  return *(unsigned short*)&b;
}
static __device__ __forceinline__ float bflo(unsigned int u) {
  return __uint_as_float(u << 16);
}
static __device__ __forceinline__ float bfhi(unsigned int u) {
  return __uint_as_float(u & 0xffff0000u);
}

// ---------------------------------------------------------------------------
// K0: pack weights into MFMA B-fragment order (blocks 0-39) + edge histogram
// (blocks 40+).  hist atomicAdd return value = edge's within-node slot ->
// eoff[e]; removes ALL atomics from the scatter phase (round-9 proven).
// ---------------------------------------------------------------------------
__global__ __launch_bounds__(256) void k_frag_hist(
    const float* __restrict__ enc_w, const float* __restrict__ M_w,
    const float* __restrict__ U_w,
    unsigned short* __restrict__ encf, unsigned short* __restrict__ Pf,
    unsigned short* __restrict__ Qf, unsigned short* __restrict__ Uf,
    const int* __restrict__ ei, int* __restrict__ cnt,
    int* __restrict__ eoff, int E) {
  const int b = blockIdx.x;
  if (b >= 40) {
    const int e = (b - 40) * 256 + threadIdx.x;
    if (e < E) eoff[e] = atomicAdd(&cnt[ei[E + e]], 1);
    return;
  }
  const float* W; unsigned short* F; int KS; int lb;
  if (b < 8)       { W = enc_w + HD;     F = encf; KS = 4; lb = b; }
  else if (b < 16) { W = M_w;            F = Pf;   KS = 4; lb = b - 8; }
  else if (b < 24) { W = M_w + HD * HD;  F = Qf;   KS = 4; lb = b - 16; }
  else             { W = U_w;            F = Uf;   KS = 8; lb = b - 24; }
  const int gid = lb * 256 + threadIdx.x;
  const int lane = gid & 63;
  const int ks = (gid >> 6) % KS;
  const int tile = gid / (64 * KS);
  const int col = tile * 16 + (lane & 15);
  const int k0 = ks * 32 + (lane >> 4) * 8;
  unsigned short v[8];
#pragma unroll
  for (int j = 0; j < 8; ++j) v[j] = f2bf(W[(size_t)(k0 + j) * HD + col]);
  unsigned short* dst = F + ((size_t)(tile * KS + ks) * 64 + lane) * 8;
#pragma unroll
  for (int j = 0; j < 8; ++j) dst[j] = v[j];
}

// ---------------------------------------------------------------------------
// K_scan1: single-dispatch scan via decoupled lookback (round-8/9 proven).
// row_ptr = exclusive prefix, cursor = inclusive prefix (= row_end).
// ---------------------------------------------------------------------------
__global__ __launch_bounds__(256) void k_scan1(
    int* __restrict__ cursor, int* __restrict__ row_ptr,
    unsigned long long* __restrict__ flags, int N) {
  __shared__ int s[256];
  __shared__ int poff_sh;
  const int t = threadIdx.x, b = blockIdx.x;
  const int base = b * 1024 + t * 4;
  int v[4], sum = 0;
#pragma unroll
  for (int i = 0; i < 4; ++i) {
    v[i] = (base + i < N) ? cursor[base + i] : 0;
    sum += v[i];
  }
  s[t] = sum;
  __syncthreads();
  for (int off = 1; off < 256; off <<= 1) {
    int xv = (t >= off) ? s[t - off] : 0;
    __syncthreads();
    if (t >= off) s[t] += xv;
    __syncthreads();
  }
  if (t == 0)
    atomicExch(&flags[b], ((unsigned long long)(unsigned)s[255] << 32) | 1ull);
  if (t < 64) {
    int acc = 0;
    if (t < b) {
      unsigned long long f;
      do { f = atomicAdd(&flags[t], 0ull); } while (!(f & 1ull));
      acc = (int)(f >> 32);
    }
#pragma unroll
    for (int o = 32; o > 0; o >>= 1) acc += __shfl_down(acc, o);
    if (t == 0) poff_sh = acc;
  }
  __syncthreads();
  int run = s[t] - sum + poff_sh;
#pragma unroll
  for (int i = 0; i < 4; ++i) {
    if (base + i < N) {
      row_ptr[base + i] = run;          // exclusive (row start)
      cursor[base + i]  = run + v[i];   // inclusive (row end)
      run += v[i];
    }
  }
}

// ---------------------------------------------------------------------------
// K1: merged atomic-free scatter (blocks 0..eb-1) + MFMA encoder/P/Q
// (blocks eb..).  (round-9 proven)
// ---------------------------------------------------------------------------
__global__ __launch_bounds__(256, 4) void k_scatter_enc(
    const int* __restrict__ ei, const float* __restrict__ edge_attr,
    const int* __restrict__ row_ptr, const int* __restrict__ eoff,
    int2* __restrict__ epack, int E, int eb,
    const float* __restrict__ x, const float* __restrict__ pre_h,
    const float* __restrict__ enc_w, const float* __restrict__ enc_b,
    const float* __restrict__ M_b,
    const unsigned short* __restrict__ encf, const unsigned short* __restrict__ Pf,
    const unsigned short* __restrict__ Qf,
    unsigned short* __restrict__ zg, unsigned short* __restrict__ Pg,
    unsigned short* __restrict__ Qg) {
  __shared__ unsigned short phs[16 * APAD];  // pre_h bf16; later P staging
  __shared__ unsigned short zsh[16 * APAD];  // z bf16; later Q staging
  __shared__ float xs[16];
  const int t = threadIdx.x;

  if (blockIdx.x < (unsigned)eb) {
    const int e = blockIdx.x * 256 + t;
    if (e < E) {
      const int tgt = ei[E + e];
      const int pos = row_ptr[tgt] + eoff[e];
      epack[pos] = make_int2(ei[e], __float_as_int(edge_attr[e]));
    }
    return;
  }

  const int n0 = (blockIdx.x - eb) * 16;
  {
    const int r = t >> 4, c0 = (t & 15) * 8;
    const float4 a = *(const float4*)&pre_h[(size_t)(n0 + r) * HD + c0];
    const float4 b = *(const float4*)&pre_h[(size_t)(n0 + r) * HD + c0 + 4];
    unsigned short* d = &phs[r * APAD + c0];
    d[0] = f2bf(a.x); d[1] = f2bf(a.y); d[2] = f2bf(a.z); d[3] = f2bf(a.w);
    d[4] = f2bf(b.x); d[5] = f2bf(b.y); d[6] = f2bf(b.z); d[7] = f2bf(b.w);
  }
  if (t < 16) xs[t] = x[n0 + t];
  __syncthreads();

  const int w = t >> 6, l = t & 63;
  const int m = l & 15, q = l >> 4;

  bf16x8 af[4];
#pragma unroll
  for (int ks = 0; ks < 4; ++ks)
    af[ks] = *(const bf16x8*)&phs[m * APAD + ks * 32 + q * 8];
  f32x4 acc[2] = {{0, 0, 0, 0}, {0, 0, 0, 0}};
#pragma unroll
  for (int tt = 0; tt < 2; ++tt) {
    const int tn = 2 * w + tt;
#pragma unroll
    for (int ks = 0; ks < 4; ++ks) {
      const bf16x8 bf = *(const bf16x8*)&encf[((size_t)(tn * 4 + ks) * 64 + l) * 8];
      acc[tt] = __builtin_amdgcn_mfma_f32_16x16x32_bf16(af[ks], bf, acc[tt], 0, 0, 0);
    }
  }
#pragma unroll
  for (int tt = 0; tt < 2; ++tt) {
    const int col = (2 * w + tt) * 16 + m;
    const float bb = enc_b[col];
    const float w0 = enc_w[col];  // row 0 (x feature)
#pragma unroll
    for (int r = 0; r < 4; ++r) {
      const int row = q * 4 + r;
      const float zv = fmaxf(acc[tt][r] + bb + xs[row] * w0, 0.0f);
      zsh[row * APAD + col] = f2bf(zv);
    }
  }
  __syncthreads();

  bf16x8 az[4];
#pragma unroll
  for (int ks = 0; ks < 4; ++ks)
    az[ks] = *(const bf16x8*)&zsh[m * APAD + ks * 32 + q * 8];
  {
    const int r = t >> 4, c0 = (t & 15) * 8;
    *(uint4*)&zg[(size_t)(n0 + r) * HD + c0] = *(const uint4*)&zsh[r * APAD + c0];
  }
  __syncthreads();

  f32x4 pacc[2] = {{0, 0, 0, 0}, {0, 0, 0, 0}};
  f32x4 qacc[2] = {{0, 0, 0, 0}, {0, 0, 0, 0}};
#pragma unroll
  for (int tt = 0; tt < 2; ++tt) {
    const int tn = 2 * w + tt;
#pragma unroll
    for (int ks = 0; ks < 4; ++ks) {
      const bf16x8 bp = *(const bf16x8*)&Pf[((size_t)(tn * 4 + ks) * 64 + l) * 8];
      const bf16x8 bq = *(const bf16x8*)&Qf[((size_t)(tn * 4 + ks) * 64 + l) * 8];
      pacc[tt] = __builtin_amdgcn_mfma_f32_16x16x32_bf16(az[ks], bp, pacc[tt], 0, 0, 0);
      qacc[tt] = __builtin_amdgcn_mfma_f32_16x16x32_bf16(az[ks], bq, qacc[tt], 0, 0, 0);
    }
  }
#pragma unroll
  for (int tt = 0; tt < 2; ++tt) {
    const int col = (2 * w + tt) * 16 + m;
    const float mb = M_b[col];
#pragma unroll
    for (int r = 0; r < 4; ++r) {
      const int row = q * 4 + r;
      phs[row * APAD + col] = f2bf(pacc[tt][r] + mb);  // P staging (bias folded)
      zsh[row * APAD + col] = f2bf(qacc[tt][r]);       // Q staging
    }
  }
  __syncthreads();
  {
    const int r = t >> 4, c0 = (t & 15) * 8;
    *(uint4*)&Pg[(size_t)(n0 + r) * HD + c0] = *(const uint4*)&phs[r * APAD + c0];
    *(uint4*)&Qg[(size_t)(n0 + r) * HD + c0] = *(const uint4*)&zsh[r * APAD + c0];
  }
}

// ---------------------------------------------------------------------------
// K2: fused gather-max + U-GEMM + decoder.  32 nodes/block, 4 waves
// (round-9 traffic shape -- round 10 proved more blocks doubles traffic).
// NEW: DUAL-NODE INTERLEAVED gather -- both nodes' 8-edge batches issued
// together (16 uint4 = 256B/lane in flight, sequential gather rounds 4->2).
// Round-9's serial i-loop was compiler-serialized at VGPR=40;
// launch_bounds(256,4) raises the cap so both batches stay live.
// Clamped indices (group-uniform) handle short/empty rows: max idempotent.
// ---------------------------------------------------------------------------
__global__ __launch_bounds__(256, 4) void k_gu(
    const unsigned short* __restrict__ zg, const unsigned short* __restrict__ Pg,
    const unsigned short* __restrict__ Qg, const float* __restrict__ w_attr,
    const int* __restrict__ row_ptr, const int* __restrict__ row_end,
    const int2* __restrict__ epack, const unsigned short* __restrict__ Uf,
    const float* __restrict__ U_b, const float* __restrict__ dec_w,
    const float* __restrict__ dec_b,
    float* __restrict__ h_out, float* __restrict__ y_out,
    float* __restrict__ hpart, int N) {
  __shared__ unsigned short zsh[32 * APAD];
  __shared__ unsigned short ash[32 * APAD];
  __shared__ float hcol[HD];
  __shared__ float dacc[32];
  __shared__ float pr[32][8];
  const int t = threadIdx.x;
  const int n0 = blockIdx.x * 32;

  {
    const int r = t >> 3, c0 = (t & 7) * 16;
    const int n = min(n0 + r, N - 1);
    *(uint4*)&zsh[r * APAD + c0]     = *(const uint4*)&zg[(size_t)n * HD + c0];
    *(uint4*)&zsh[r * APAD + c0 + 8] = *(const uint4*)&zg[(size_t)n * HD + c0 + 8];
  }
  if (t < 32) dacc[t] = 0.0f;
  if (t < HD) hcol[t] = 0.0f;

  const int w = t >> 6, l = t & 63;
  const int g = l >> 4, j = l & 15;

  float wv[8];
  {
    const float4 wa = *(const float4*)&w_attr[j * 8];
    const float4 wb = *(const float4*)&w_attr[j * 8 + 4];
    wv[0] = wa.x; wv[1] = wa.y; wv[2] = wa.z; wv[3] = wa.w;
    wv[4] = wb.x; wv[5] = wb.y; wv[6] = wb.z; wv[7] = wb.w;
  }
  {
    const int r0 = w * 8 + g * 2, r1 = r0 + 1;
    const int nn0 = n0 + r0, nn1 = n0 + r1;
    const int rs0 = row_ptr[min(nn0, N - 1)], re0 = row_end[min(nn0, N - 1)];
    const int rs1 = row_ptr[min(nn1, N - 1)], re1 = row_end[min(nn1, N - 1)];
    const bool v0 = re0 > rs0, v1 = re1 > rs1;
    float ac0[8], ac1[8];
#pragma unroll
    for (int c = 0; c < 8; ++c) { ac0[c] = -INFINITY; ac1[c] = -INFINITY; }
    const int nb0 = v0 ? ((re0 - rs0 + 7) >> 3) : 0;
    const int nb1 = v1 ? ((re1 - rs1 + 7) >> 3) : 0;
    const int nbat = max(nb0, nb1);
    int e0 = rs0, e1 = rs1;
    for (int b = 0; b < nbat; ++b) {
      int2 pk0[8], pk1[8];
#pragma unroll
      for (int u = 0; u < 8; ++u) {
        pk0[u] = epack[v0 ? min(e0 + u, re0 - 1) : 0];
        pk1[u] = epack[v1 ? min(e1 + u, re1 - 1) : 0];
      }
      uint4 qv0[8], qv1[8];
#pragma unroll
      for (int u = 0; u < 8; ++u)
        qv0[u] = *(const uint4*)&Qg[(size_t)pk0[u].x * HD + j * 8];
#pragma unroll
      for (int u = 0; u < 8; ++u)
        qv1[u] = *(const uint4*)&Qg[(size_t)pk1[u].x * HD + j * 8];
#pragma unroll
      for (int u = 0; u < 8; ++u) {
        const float a = __int_as_float(pk0[u].y);
        const unsigned int qq[4] = {qv0[u].x, qv0[u].y, qv0[u].z, qv0[u].w};
#pragma unroll
        for (int c = 0; c < 4; ++c) {
          ac0[2 * c]     = fmaxf(ac0[2 * c],     fmaf(a, wv[2 * c],     bflo(qq[c])));
          ac0[2 * c + 1] = fmaxf(ac0[2 * c + 1], fmaf(a, wv[2 * c + 1], bfhi(qq[c])));
        }
      }
#pragma unroll
      for (int u = 0; u < 8; ++u) {
        const float a = __int_as_float(pk1[u].y);
        const unsigned int qq[4] = {qv1[u].x, qv1[u].y, qv1[u].z, qv1[u].w};
#pragma unroll
        for (int c = 0; c < 4; ++c) {
          ac1[2 * c]     = fmaxf(ac1[2 * c],     fmaf(a, wv[2 * c],     bflo(qq[c])));
          ac1[2 * c + 1] = fmaxf(ac1[2 * c + 1], fmaf(a, wv[2 * c + 1], bfhi(qq[c])));
        }
      }
      e0 += 8; e1 += 8;
    }
    // epilogue node0: P add + relu + pack + LDS store
    {
      float res[8];
      if (nn0 < N && v0) {
        const uint4 pv = *(const uint4*)&Pg[(size_t)nn0 * HD + j * 8];
        const unsigned int pp[4] = {pv.x, pv.y, pv.z, pv.w};
#pragma unroll
        for (int c = 0; c < 4; ++c) {
          res[2 * c]     = fmaxf(bflo(pp[c]) + ac0[2 * c],     0.0f);
          res[2 * c + 1] = fmaxf(bfhi(pp[c]) + ac0[2 * c + 1], 0.0f);
        }
      } else {
#pragma unroll
        for (int c = 0; c < 8; ++c) res[c] = 0.0f;
      }
      uint4 st;
      st.x = (unsigned)f2bf(res[0]) | ((unsigned)f2bf(res[1]) << 16);
      st.y = (unsigned)f2bf(res[2]) | ((unsigned)f2bf(res[3]) << 16);
      st.z = (unsigned)f2bf(res[4]) | ((unsigned)f2bf(res[5]) << 16);
      st.w = (unsigned)f2bf(res[6]) | ((unsigned)f2bf(res[7]) << 16);
      *(uint4*)&ash[r0 * APAD + j * 8] = st;
    }
    // epilogue node1
    {
      float res[8];
      if (nn1 < N && v1) {
        const uint4 pv = *(const uint4*)&Pg[(size_t)nn1 * HD + j * 8];
        const unsigned int pp[4] = {pv.x, pv.y, pv.z, pv.w};
#pragma unroll
        for (int c = 0; c < 4; ++c) {
          res[2 * c]     = fmaxf(bflo(pp[c]) + ac1[2 * c],     0.0f);
          res[2 * c + 1] = fmaxf(bfhi(pp[c]) + ac1[2 * c + 1], 0.0f);
        }
      } else {
#pragma unroll
        for (int c = 0; c < 8; ++c) res[c] = 0.0f;
      }
      uint4 st;
      st.x = (unsigned)f2bf(res[0]) | ((unsigned)f2bf(res[1]) << 16);
      st.y = (unsigned)f2bf(res[2]) | ((unsigned)f2bf(res[3]) << 16);
      st.z = (unsigned)f2bf(res[4]) | ((unsigned)f2bf(res[5]) << 16);
      st.w = (unsigned)f2bf(res[6]) | ((unsigned)f2bf(res[7]) << 16);
      *(uint4*)&ash[r1 * APAD + j * 8] = st;
    }
  }
  __syncthreads();

  const int mt = w & 1, nh = w >> 1;
  const int m = mt * 16 + (l & 15), q = l >> 4;
  bf16x8 afz[4], afa[4];
#pragma unroll
  for (int ks = 0; ks < 4; ++ks) {
    afz[ks] = *(const bf16x8*)&zsh[m * APAD + ks * 32 + q * 8];
    afa[ks] = *(const bf16x8*)&ash[m * APAD + ks * 32 + q * 8];
  }
  f32x4 acc4[4] = {{0, 0, 0, 0}, {0, 0, 0, 0}, {0, 0, 0, 0}, {0, 0, 0, 0}};
#pragma unroll
  for (int tt = 0; tt < 4; ++tt) {
    const int tn = nh * 4 + tt;
#pragma unroll
    for (int ks = 0; ks < 8; ++ks) {
      const bf16x8 bf = *(const bf16x8*)&Uf[((size_t)(tn * 8 + ks) * 64 + l) * 8];
      const bf16x8 a = (ks < 4) ? afz[ks] : afa[ks - 4];
      acc4[tt] = __builtin_amdgcn_mfma_f32_16x16x32_bf16(a, bf, acc4[tt], 0, 0, 0);
    }
  }
  float dp[4] = {0.0f, 0.0f, 0.0f, 0.0f};
#pragma unroll
  for (int tt = 0; tt < 4; ++tt) {
    const int col = (nh * 4 + tt) * 16 + (l & 15);
    const float ub = U_b[col];
    const float dw = dec_w[HD + col];
    float s4 = 0.0f;
#pragma unroll
    for (int r = 0; r < 4; ++r) {
      const int rowl = mt * 16 + q * 4 + r;
      const int n = n0 + rowl;
      float hv = fmaxf(acc4[tt][r] + ub, 0.0f);
      if (n < N) h_out[(size_t)n * HD + col] = hv; else hv = 0.0f;
      s4 += hv;
      dp[r] += hv * dw;
    }
    atomicAdd(&hcol[col], s4);
  }
#pragma unroll
  for (int off = 1; off < 16; off <<= 1) {
#pragma unroll
    for (int r = 0; r < 4; ++r) dp[r] += __shfl_xor(dp[r], off);
  }
  if ((l & 15) == 0) {
#pragma unroll
    for (int r = 0; r < 4; ++r) atomicAdd(&dacc[mt * 16 + q * 4 + r], dp[r]);
  }
  {
    const int r2 = t >> 3, s = t & 7;
    float part = 0.0f;
#pragma unroll
    for (int c = 0; c < 8; ++c) {
      const int kk = s * 16 + 2 * c;
      const unsigned int zu = *(const unsigned int*)&zsh[r2 * APAD + kk];
      part += bflo(zu) * dec_w[kk] + bfhi(zu) * dec_w[kk + 1];
    }
    pr[r2][s] = part;
  }
  __syncthreads();

  if (t < HD) hpart[(size_t)blockIdx.x * HD + t] = hcol[t];
  if (t < 32 && n0 + t < N) {
    float d = dec_b[0] + dacc[t];
#pragma unroll
    for (int s = 0; s < 8; ++s) d += pr[t][s];
    y_out[n0 + t] = 1.0f / (1.0f + expf(-d));
  }
}

// ---------------------------------------------------------------------------
// K3: parallel hpart reduction + terminator in ONE dispatch (round-8/9 proven).
// ---------------------------------------------------------------------------
__global__ __launch_bounds__(256) void k_hred_ter(
    const float* __restrict__ hpart, float* __restrict__ hsum,
    int* __restrict__ done,
    const float* __restrict__ ter_w, const float* __restrict__ ter_b,
    float* __restrict__ out, float invN, int NB, int nblk) {
  __shared__ float sh[HD];
  __shared__ float r2[2];
  __shared__ int last;
  const int t = threadIdx.x;
  const int col = t & (HD - 1);
  const int half = t >> 7;
  float acc = 0.0f;
  for (int r = blockIdx.x * 2 + half; r < NB; r += nblk * 2)
    acc += hpart[(size_t)r * HD + col];
  if (half) sh[col] = acc;
  __syncthreads();
  if (!half) atomicAdd(&hsum[col], acc + sh[col]);
  __threadfence();
  __syncthreads();
  if (t == 0) last = (atomicAdd(done, 1) == nblk - 1);
  __syncthreads();
  if (!last) return;
  float v = 0.0f;
  if (t < HD) {
    const float cs = atomicAdd(&hsum[t], 0.0f);  // atomic load (bypass L1)
    v = (cs * invN) * (ter_w[t] + ter_w[HD + t]);
  }
#pragma unroll
  for (int o = 32; o > 0; o >>= 1) v += __shfl_down(v, o);
  if (t < HD && (t & 63) == 0) r2[t >> 6] = v;
  __syncthreads();
  if (t == 0) out[0] = r2[0] + r2[1] + ter_b[0];
}

// ---------------------------------------------------------------------------
extern "C" void kernel_launch(void* const* d_in, const int* in_sizes, int n_in,
                              void* d_out, int out_size, void* d_ws, size_t ws_size,
                              hipStream_t stream) {
  const float* x        = (const float*)d_in[0];
  const float* pre_h    = (const float*)d_in[1];
  const float* edge_attr= (const float*)d_in[2];
  const float* enc_w    = (const float*)d_in[3];
  const float* enc_b    = (const float*)d_in[4];
  const float* M_w      = (const float*)d_in[5];
  const float* M_b      = (const float*)d_in[6];
  const float* U_w      = (const float*)d_in[7];
  const float* U_b      = (const float*)d_in[8];
  const float* dec_w    = (const float*)d_in[9];
  const float* dec_b    = (const float*)d_in[10];
  const float* ter_w    = (const float*)d_in[11];
  const float* ter_b    = (const float*)d_in[12];
  const int*   edge_idx = (const int*)d_in[13];

  const int N = in_sizes[0];      // 50000
  const int E = in_sizes[2];      // 600000
  const size_t NH = (size_t)N * HD;

  float* out = (float*)d_out;
  float* h_out = out;             // [0, N*H)
  float* y_out = out + NH;        // [N*H, N*H+N)
  float* ter_out = out + NH + N;

  // ws layout (bf16): zg | Pg | Qg | cursor(N) | flags(64 ull) | done(2 int)
  //                   | hsum(128 f) | row_ptr(N) | epack(E int2) | eoff(E int)
  //                   | encf | Pf | Qf | Uf | hpart
  unsigned short* zg = (unsigned short*)d_ws;
  unsigned short* Pg = zg + NH;
  unsigned short* Qg = Pg + NH;
  int*   cursor   = (int*)(Qg + NH);
  unsigned long long* flags = (unsigned long long*)(cursor + N);  // N*4 %8==0
  int*   done     = (int*)(flags + 64);
  float* hsum     = (float*)(done + 2);
  int*   row_ptr  = (int*)(hsum + HD);
  int2*  epack    = (int2*)(row_ptr + N);
  int*   eoff     = (int*)(epack + E);
  unsigned short* encf = (unsigned short*)(eoff + E);
  unsigned short* Pf   = encf + 8 * 4 * 64 * 8;
  unsigned short* Qf   = Pf + 8 * 4 * 64 * 8;
  unsigned short* Uf   = Qf + 8 * 4 * 64 * 8;
  float* hpart = (float*)(Uf + 16 * 256 * 8);

  const size_t zero_bytes = (size_t)N * 4 + 64 * 8 + 2 * 4 + HD * 4;
  hipMemsetAsync(cursor, 0, zero_bytes, stream);

  const int scan_blocks = (N + 1023) / 1024;  // 49
  const int eb = (E + 255) / 256;             // 2344
  const int nb32 = (N + 31) / 32;             // 1563

  k_frag_hist<<<40 + eb, 256, 0, stream>>>(enc_w, M_w, U_w, encf, Pf, Qf, Uf,
                                           edge_idx, cursor, eoff, E);
  k_scan1<<<scan_blocks, 256, 0, stream>>>(cursor, row_ptr, flags, N);
  k_scatter_enc<<<eb + N / 16, 256, 0, stream>>>(
      edge_idx, edge_attr, row_ptr, eoff, epack, E, eb,
      x, pre_h, enc_w, enc_b, M_b, encf, Pf, Qf, zg, Pg, Qg);
  k_gu<<<nb32, 256, 0, stream>>>(
      zg, Pg, Qg, M_w + 256 * HD, row_ptr, cursor, epack, Uf,
      U_b, dec_w, dec_b, h_out, y_out, hpart, N);
  k_hred_ter<<<64, 256, 0, stream>>>(hpart, hsum, done, ter_w, ter_b, ter_out,
                                     1.0f / (float)N, nb32, 64);
}